// Round 1
// baseline (62.877 us; speedup 1.0000x reference)
//
#include <hip/hip_runtime.h>

#define EPS        1e-5f
#define DW_THRESH  4.0f
#define PW_THRESH  0.001f
#define CIN        512
#define COUT       512
#define HWPLANE    784   // 28*28
#define W28        28

// ---------------------------------------------------------------------------
// Pass 1: depthwise 3x3 + bias + BN1 + ReLU -> per-(b,c) plane amax -> flag bit
// One block per (b,c) plane. Writes ONLY the active-bit mask (no h buffer).
// ---------------------------------------------------------------------------
__global__ __launch_bounds__(256) void dw_flags_kernel(
    const float* __restrict__ x,
    const float* __restrict__ dw_w, const float* __restrict__ dw_b,
    const float* __restrict__ bn1_g, const float* __restrict__ bn1_b,
    const float* __restrict__ bn1_m, const float* __restrict__ bn1_v,
    unsigned int* __restrict__ mask)
{
    const int bid = blockIdx.x;            // b*512 + c
    const int b   = bid >> 9;
    const int c   = bid & 511;
    const int tid = threadIdx.x;

    __shared__ float sx[30 * 30];
    __shared__ float red[4];

    // zero the whole padded tile (covers the halo border)
    for (int i = tid; i < 900; i += 256) sx[i] = 0.0f;
    __syncthreads();

    // stage interior: 196 float4 loads (coalesced), scalar LDS writes
    const float* xp = x + (size_t)bid * HWPLANE;
    if (tid < 196) {
        const float4 v = ((const float4*)xp)[tid];
        const int y  = tid / 7;
        const int x0 = (tid % 7) * 4;
        float* d = &sx[(y + 1) * 30 + x0 + 1];
        d[0] = v.x; d[1] = v.y; d[2] = v.z; d[3] = v.w;
    }

    // per-channel constants (block-uniform loads, cached)
    const float inv1 = bn1_g[c] * rsqrtf(bn1_v[c] + EPS);
    const float c1   = (dw_b[c] - bn1_m[c]) * inv1 + bn1_b[c];
    float w[9];
    #pragma unroll
    for (int k = 0; k < 9; ++k) w[k] = dw_w[c * 9 + k];

    __syncthreads();

    float amax = 0.0f;   // ReLU output >= 0, so 0 is the identity for max
    if (tid < 196) {
        const int xx = tid % 28;           // column
        const int ys = (tid / 28) * 4;     // 4-pixel column strip
        // register-stage the 6x3 window (padded rows ys..ys+5, cols xx..xx+2)
        float r[6][3];
        #pragma unroll
        for (int j = 0; j < 6; ++j)
            #pragma unroll
            for (int k = 0; k < 3; ++k)
                r[j][k] = sx[(ys + j) * 30 + xx + k];
        #pragma unroll
        for (int i = 0; i < 4; ++i) {
            float acc = 0.0f;
            #pragma unroll
            for (int dy = 0; dy < 3; ++dy)
                #pragma unroll
                for (int dx = 0; dx < 3; ++dx)
                    acc = fmaf(w[dy * 3 + dx], r[i + dy][dx], acc);
            float v = fmaf(acc, inv1, c1);
            v = v > 0.0f ? v : 0.0f;       // ReLU
            amax = fmaxf(amax, v);
        }
    }

    // block max-reduce: wave shuffle then cross-wave via LDS
    #pragma unroll
    for (int off = 32; off > 0; off >>= 1)
        amax = fmaxf(amax, __shfl_down(amax, off, 64));
    if ((tid & 63) == 0) red[tid >> 6] = amax;
    __syncthreads();
    if (tid == 0) {
        const float m = fmaxf(fmaxf(red[0], red[1]), fmaxf(red[2], red[3]));
        if (m >= DW_THRESH)  // prune iff amax < thresh (strict), keep otherwise
            atomicOr(&mask[(b << 4) + (c >> 5)], 1u << (c & 31));
    }
}

// ---------------------------------------------------------------------------
// Pass 2: pointwise 1x1 over ACTIVE channels only (+bias+BN2+ReLU+prune).
// One block per (b,co) output plane. Fast path (no active ci): constant fill.
// General path: recompute active h-planes inline from x (active planes pass
// through pruning unchanged, so per-pixel recompute is exact).
// ---------------------------------------------------------------------------
__global__ __launch_bounds__(256) void pw_kernel(
    const float* __restrict__ x,
    const float* __restrict__ dw_w, const float* __restrict__ dw_b,
    const float* __restrict__ bn1_g, const float* __restrict__ bn1_b,
    const float* __restrict__ bn1_m, const float* __restrict__ bn1_v,
    const float* __restrict__ pw_w, const float* __restrict__ pw_b,
    const float* __restrict__ bn2_g, const float* __restrict__ bn2_b,
    const float* __restrict__ bn2_m, const float* __restrict__ bn2_v,
    const unsigned int* __restrict__ mask,
    float* __restrict__ out)
{
    const int bid = blockIdx.x;            // b*512 + co
    const int b   = bid >> 9;
    const int co  = bid & 511;
    const int tid = threadIdx.x;

    __shared__ unsigned int smask[16];
    __shared__ float sx[30 * 30];
    __shared__ float red[4];
    __shared__ float sfinal;

    if (tid < 16) smask[tid] = mask[(b << 4) + tid];
    __syncthreads();

    unsigned int any = 0;
    #pragma unroll
    for (int k = 0; k < 16; ++k) any |= smask[k];

    const float inv2 = bn2_g[co] * rsqrtf(bn2_v[co] + EPS);
    const float c2   = (pw_b[co] - bn2_m[co]) * inv2 + bn2_b[co];
    float* op = out + (size_t)bid * HWPLANE;

    if (any == 0u) {
        // all input planes pruned: out = prune(relu(c2)) — constant plane
        float v = c2 > 0.0f ? c2 : 0.0f;
        if (v < PW_THRESH) v = 0.0f;
        if (tid < 196) ((float4*)op)[tid] = make_float4(v, v, v, v);
        return;
    }

    // ---- general path (rare on this data, fully correct) ----
    for (int i = tid; i < 900; i += 256) sx[i] = 0.0f;   // border zeros

    float acc[4] = {0.f, 0.f, 0.f, 0.f};
    const int xx = tid % 28;
    const int ys = (tid / 28) * 4;

    for (int ci = 0; ci < CIN; ++ci) {
        if (!((smask[ci >> 5] >> (ci & 31)) & 1u)) continue;  // uniform branch
        __syncthreads();   // protect sx before overwrite (also covers zero-init)
        const float* xp = x + ((size_t)(b * CIN + ci)) * HWPLANE;
        if (tid < 196) {
            const float4 v = ((const float4*)xp)[tid];
            const int y  = tid / 7;
            const int x0 = (tid % 7) * 4;
            float* d = &sx[(y + 1) * 30 + x0 + 1];
            d[0] = v.x; d[1] = v.y; d[2] = v.z; d[3] = v.w;
        }
        const float inv1 = bn1_g[ci] * rsqrtf(bn1_v[ci] + EPS);
        const float c1   = (dw_b[ci] - bn1_m[ci]) * inv1 + bn1_b[ci];
        const float wco  = pw_w[co * CIN + ci];
        float w[9];
        #pragma unroll
        for (int k = 0; k < 9; ++k) w[k] = dw_w[ci * 9 + k];
        __syncthreads();
        if (tid < 196) {
            float r[6][3];
            #pragma unroll
            for (int j = 0; j < 6; ++j)
                #pragma unroll
                for (int k = 0; k < 3; ++k)
                    r[j][k] = sx[(ys + j) * 30 + xx + k];
            #pragma unroll
            for (int i = 0; i < 4; ++i) {
                float a = 0.0f;
                #pragma unroll
                for (int dy = 0; dy < 3; ++dy)
                    #pragma unroll
                    for (int dx = 0; dx < 3; ++dx)
                        a = fmaf(w[dy * 3 + dx], r[i + dy][dx], a);
                float hv = fmaf(a, inv1, c1);
                hv = hv > 0.0f ? hv : 0.0f;
                acc[i] = fmaf(wco, hv, acc[i]);
            }
        }
    }

    // epilogue: BN2 + ReLU, plane amax, prune, write
    float v[4];
    float amax = 0.0f;
    if (tid < 196) {
        #pragma unroll
        for (int i = 0; i < 4; ++i) {
            float t = fmaf(acc[i], inv2, c2);
            t = t > 0.0f ? t : 0.0f;
            v[i] = t;
            amax = fmaxf(amax, t);
        }
    }
    #pragma unroll
    for (int off = 32; off > 0; off >>= 1)
        amax = fmaxf(amax, __shfl_down(amax, off, 64));
    if ((tid & 63) == 0) red[tid >> 6] = amax;
    __syncthreads();
    if (tid == 0)
        sfinal = fmaxf(fmaxf(red[0], red[1]), fmaxf(red[2], red[3]));
    __syncthreads();
    const bool zero = sfinal < PW_THRESH;
    if (tid < 196) {
        #pragma unroll
        for (int i = 0; i < 4; ++i)
            op[(ys + i) * 28 + xx] = zero ? 0.0f : v[i];
    }
}

extern "C" void kernel_launch(void* const* d_in, const int* in_sizes, int n_in,
                              void* d_out, int out_size, void* d_ws, size_t ws_size,
                              hipStream_t stream)
{
    const float* x     = (const float*)d_in[0];
    const float* dw_w  = (const float*)d_in[1];
    const float* dw_b  = (const float*)d_in[2];
    const float* bn1_g = (const float*)d_in[3];
    const float* bn1_b = (const float*)d_in[4];
    const float* bn1_m = (const float*)d_in[5];
    const float* bn1_v = (const float*)d_in[6];
    const float* pw_w  = (const float*)d_in[7];
    const float* pw_b  = (const float*)d_in[8];
    const float* bn2_g = (const float*)d_in[9];
    const float* bn2_b = (const float*)d_in[10];
    const float* bn2_m = (const float*)d_in[11];
    const float* bn2_v = (const float*)d_in[12];

    unsigned int* mask = (unsigned int*)d_ws;  // 64 batches x 16 words = 4 KB

    // re-zero the mask every call (graph replays re-run this memset)
    hipMemsetAsync(mask, 0, 64 * 16 * sizeof(unsigned int), stream);

    dw_flags_kernel<<<64 * 512, 256, 0, stream>>>(
        x, dw_w, dw_b, bn1_g, bn1_b, bn1_m, bn1_v, mask);

    pw_kernel<<<64 * 512, 256, 0, stream>>>(
        x, dw_w, dw_b, bn1_g, bn1_b, bn1_m, bn1_v,
        pw_w, pw_b, bn2_g, bn2_b, bn2_m, bn2_v,
        mask, (float*)d_out);
}

// Round 2
// 60.496 us; speedup vs baseline: 1.0394x; 1.0394x over previous
//
#include <hip/hip_runtime.h>

#define EPS        1e-5f
#define DW_THRESH  4.0f
#define PW_THRESH  0.001f
#define CIN        512
#define COUT       512
#define HWPLANE    784   // 28*28

// ---------------------------------------------------------------------------
// Pass 1: depthwise 3x3 + bias + BN1 + ReLU -> per-plane amax -> flag bits.
// One block per (b, 32-channel word): 64*16 = 1024 blocks. Double-buffered
// LDS plane with register prefetch of the next plane. Thread 0 assembles the
// 32-bit flag word and writes it directly (no memset, no atomics).
// ---------------------------------------------------------------------------
__global__ __launch_bounds__(256) void dw_flags_kernel(
    const float* __restrict__ x,
    const float* __restrict__ dw_w, const float* __restrict__ dw_b,
    const float* __restrict__ bn1_g, const float* __restrict__ bn1_b,
    const float* __restrict__ bn1_m, const float* __restrict__ bn1_v,
    unsigned int* __restrict__ mask)
{
    const int bid  = blockIdx.x;           // b*16 + word
    const int word = bid & 15;
    const int tid  = threadIdx.x;

    __shared__ float sx[2][30 * 30];
    __shared__ float red[4];

    // zero both padded tiles once (interior is overwritten every iteration,
    // the halo border stays zero for the whole loop)
    for (int i = tid; i < 900; i += 256) { sx[0][i] = 0.0f; sx[1][i] = 0.0f; }

    const float* xp0 = x + (size_t)bid * 32 * HWPLANE;  // 32 contiguous planes

    int y = 0, x0 = 0;
    float4 v = make_float4(0.f, 0.f, 0.f, 0.f);
    if (tid < 196) {
        y  = tid / 7;
        x0 = (tid % 7) * 4;
        v  = ((const float4*)xp0)[tid];    // prefetch plane 0
    }
    const int xx = tid % 28;               // column
    const int ys = (tid / 28) * 4;         // 4-row strip base

    __syncthreads();                       // borders zeroed

    unsigned int flags = 0;

    for (int it = 0; it < 32; ++it) {
        const int buf = it & 1;
        if (tid < 196) {
            float* d = &sx[buf][(y + 1) * 30 + x0 + 1];
            d[0] = v.x; d[1] = v.y; d[2] = v.z; d[3] = v.w;
            if (it < 31)                   // issue next plane's load early
                v = ((const float4*)(xp0 + (size_t)(it + 1) * HWPLANE))[tid];
        }
        // per-channel uniform constants (scalar loads, L2-cached)
        const int   c    = (bid << 5) % (CIN) + it;  // == word*32 + it
        const int   cc   = word * 32 + it;
        (void)c;
        const float inv1 = bn1_g[cc] * rsqrtf(bn1_v[cc] + EPS);
        const float c1   = (dw_b[cc] - bn1_m[cc]) * inv1 + bn1_b[cc];
        float w9[9];
        #pragma unroll
        for (int k = 0; k < 9; ++k) w9[k] = dw_w[cc * 9 + k];

        __syncthreads();                   // sx[buf] visible

        float amax = 0.0f;                 // ReLU output >= 0
        if (tid < 196) {
            float r[6][3];
            #pragma unroll
            for (int j = 0; j < 6; ++j)
                #pragma unroll
                for (int k = 0; k < 3; ++k)
                    r[j][k] = sx[buf][(ys + j) * 30 + xx + k];
            #pragma unroll
            for (int i = 0; i < 4; ++i) {
                float a = 0.0f;
                #pragma unroll
                for (int dy = 0; dy < 3; ++dy)
                    #pragma unroll
                    for (int dx = 0; dx < 3; ++dx)
                        a = fmaf(w9[dy * 3 + dx], r[i + dy][dx], a);
                float t = fmaf(a, inv1, c1);
                t = t > 0.0f ? t : 0.0f;
                amax = fmaxf(amax, t);
            }
        }
        // block max-reduce
        #pragma unroll
        for (int off = 32; off > 0; off >>= 1)
            amax = fmaxf(amax, __shfl_down(amax, off, 64));
        if ((tid & 63) == 0) red[tid >> 6] = amax;
        __syncthreads();
        if (tid == 0) {
            const float m = fmaxf(fmaxf(red[0], red[1]), fmaxf(red[2], red[3]));
            if (m >= DW_THRESH) flags |= (1u << it);   // active (not pruned)
        }
    }
    if (tid == 0) mask[bid] = flags;
}

// ---------------------------------------------------------------------------
// Pass 2: pointwise 1x1 over ACTIVE channels (+bias+BN2+ReLU+prune).
// One block per (b, 32-output-channel group): 1024 blocks. Fast path (no
// active ci in the batch): 32 constant planes streamed as one contiguous
// 100 KB float4 store loop using all 256 lanes.
// ---------------------------------------------------------------------------
__global__ __launch_bounds__(256) void pw_kernel(
    const float* __restrict__ x,
    const float* __restrict__ dw_w, const float* __restrict__ dw_b,
    const float* __restrict__ bn1_g, const float* __restrict__ bn1_b,
    const float* __restrict__ bn1_m, const float* __restrict__ bn1_v,
    const float* __restrict__ pw_w, const float* __restrict__ pw_b,
    const float* __restrict__ bn2_g, const float* __restrict__ bn2_b,
    const float* __restrict__ bn2_m, const float* __restrict__ bn2_v,
    const unsigned int* __restrict__ mask,
    float* __restrict__ out)
{
    const int bid = blockIdx.x;            // b*16 + og
    const int b   = bid >> 4;
    const int og  = bid & 15;
    const int tid = threadIdx.x;

    __shared__ unsigned int smask[16];
    __shared__ float sconst[32];
    __shared__ float sx[30 * 30];
    __shared__ float red[4];
    __shared__ float sfinal;

    if (tid < 16) smask[tid] = mask[(b << 4) + tid];
    __syncthreads();

    unsigned int any = 0;
    #pragma unroll
    for (int k = 0; k < 16; ++k) any |= smask[k];

    float* ob = out + (size_t)bid * 32 * HWPLANE;   // 32 contiguous planes

    if (any == 0u) {
        // all input planes pruned: each output plane is a constant
        if (tid < 32) {
            const int   co   = og * 32 + tid;
            const float inv2 = bn2_g[co] * rsqrtf(bn2_v[co] + EPS);
            const float c2   = (pw_b[co] - bn2_m[co]) * inv2 + bn2_b[co];
            float vv = c2 > 0.0f ? c2 : 0.0f;       // ReLU
            if (vv < PW_THRESH) vv = 0.0f;          // plane prune (constant)
            sconst[tid] = vv;
        }
        __syncthreads();
        // 32 planes * 196 float4 = 6272 contiguous float4 stores
        for (int j = tid; j < 6272; j += 256) {
            const float vv = sconst[j / 196];
            ((float4*)ob)[j] = make_float4(vv, vv, vv, vv);
        }
        return;
    }

    // ---- general path (correctness only; never taken with this data) ----
    for (int i = tid; i < 900; i += 256) sx[i] = 0.0f;   // halo zeros
    const int xx = tid % 28;
    const int ys = (tid / 28) * 4;

    for (int col = 0; col < 32; ++col) {
        const int co = og * 32 + col;
        const float inv2 = bn2_g[co] * rsqrtf(bn2_v[co] + EPS);
        const float c2   = (pw_b[co] - bn2_m[co]) * inv2 + bn2_b[co];
        float acc[4] = {0.f, 0.f, 0.f, 0.f};

        for (int ci = 0; ci < CIN; ++ci) {
            if (!((smask[ci >> 5] >> (ci & 31)) & 1u)) continue;  // uniform
            __syncthreads();   // protect sx before overwrite
            const float* xp = x + ((size_t)(b * CIN + ci)) * HWPLANE;
            if (tid < 196) {
                const float4 vv = ((const float4*)xp)[tid];
                const int y  = tid / 7;
                const int x0 = (tid % 7) * 4;
                float* d = &sx[(y + 1) * 30 + x0 + 1];
                d[0] = vv.x; d[1] = vv.y; d[2] = vv.z; d[3] = vv.w;
            }
            const float inv1 = bn1_g[ci] * rsqrtf(bn1_v[ci] + EPS);
            const float c1   = (dw_b[ci] - bn1_m[ci]) * inv1 + bn1_b[ci];
            const float wco  = pw_w[co * CIN + ci];
            float w9[9];
            #pragma unroll
            for (int k = 0; k < 9; ++k) w9[k] = dw_w[ci * 9 + k];
            __syncthreads();
            if (tid < 196) {
                float r[6][3];
                #pragma unroll
                for (int j = 0; j < 6; ++j)
                    #pragma unroll
                    for (int k = 0; k < 3; ++k)
                        r[j][k] = sx[(ys + j) * 30 + xx + k];
                #pragma unroll
                for (int i = 0; i < 4; ++i) {
                    float a = 0.0f;
                    #pragma unroll
                    for (int dy = 0; dy < 3; ++dy)
                        #pragma unroll
                        for (int dx = 0; dx < 3; ++dx)
                            a = fmaf(w9[dy * 3 + dx], r[i + dy][dx], a);
                    float hv = fmaf(a, inv1, c1);
                    hv = hv > 0.0f ? hv : 0.0f;
                    acc[i] = fmaf(wco, hv, acc[i]);
                }
            }
        }

        // epilogue for this output plane
        float vout[4];
        float amax = 0.0f;
        if (tid < 196) {
            #pragma unroll
            for (int i = 0; i < 4; ++i) {
                float t = fmaf(acc[i], inv2, c2);
                t = t > 0.0f ? t : 0.0f;
                vout[i] = t;
                amax = fmaxf(amax, t);
            }
        }
        #pragma unroll
        for (int off = 32; off > 0; off >>= 1)
            amax = fmaxf(amax, __shfl_down(amax, off, 64));
        if ((tid & 63) == 0) red[tid >> 6] = amax;
        __syncthreads();
        if (tid == 0)
            sfinal = fmaxf(fmaxf(red[0], red[1]), fmaxf(red[2], red[3]));
        __syncthreads();
        const bool zero = sfinal < PW_THRESH;
        if (tid < 196) {
            float* op = ob + (size_t)col * HWPLANE;
            #pragma unroll
            for (int i = 0; i < 4; ++i)
                op[(ys + i) * 28 + xx] = zero ? 0.0f : vout[i];
        }
        __syncthreads();   // sfinal/red reuse next col
    }
}

extern "C" void kernel_launch(void* const* d_in, const int* in_sizes, int n_in,
                              void* d_out, int out_size, void* d_ws, size_t ws_size,
                              hipStream_t stream)
{
    const float* x     = (const float*)d_in[0];
    const float* dw_w  = (const float*)d_in[1];
    const float* dw_b  = (const float*)d_in[2];
    const float* bn1_g = (const float*)d_in[3];
    const float* bn1_b = (const float*)d_in[4];
    const float* bn1_m = (const float*)d_in[5];
    const float* bn1_v = (const float*)d_in[6];
    const float* pw_w  = (const float*)d_in[7];
    const float* pw_b  = (const float*)d_in[8];
    const float* bn2_g = (const float*)d_in[9];
    const float* bn2_b = (const float*)d_in[10];
    const float* bn2_m = (const float*)d_in[11];
    const float* bn2_v = (const float*)d_in[12];

    unsigned int* mask = (unsigned int*)d_ws;  // 64 batches x 16 words = 4 KB
    // every word of mask is written unconditionally by dw_flags_kernel:
    // no memset node needed.

    dw_flags_kernel<<<64 * 16, 256, 0, stream>>>(
        x, dw_w, dw_b, bn1_g, bn1_b, bn1_m, bn1_v, mask);

    pw_kernel<<<64 * 16, 256, 0, stream>>>(
        x, dw_w, dw_b, bn1_g, bn1_b, bn1_m, bn1_v,
        pw_w, pw_b, bn2_g, bn2_b, bn2_m, bn2_v,
        mask, (float*)d_out);
}

// Round 3
// 38.460 us; speedup vs baseline: 1.6349x; 1.5730x over previous
//
#include <hip/hip_runtime.h>

#define EPS        1e-5f
#define DW_THRESH  4.0f
#define PW_THRESH  0.001f
#define CIN        512
#define COUT       512
#define HWPLANE    784   // 28*28

// ---------------------------------------------------------------------------
// Pass 1: depthwise 3x3 + bias + BN1 + ReLU -> per-plane amax -> flag bits.
// One block per (b, 32-channel word): 1024 blocks, 4 waves/block.
// Each WAVE independently processes 8 planes in its own padded LDS tile:
// no __syncthreads in the hot loop, wave-internal DS ordering only.
// Per lane: 2 horizontally-adjacent pixels x 7 rows, rolling 3-row window,
// 3 x ds_read_b64 per row. Register prefetch of the next plane.
// ---------------------------------------------------------------------------
__global__ __launch_bounds__(256) void dw_flags_kernel(
    const float* __restrict__ x,
    const float* __restrict__ dw_w, const float* __restrict__ dw_b,
    const float* __restrict__ bn1_g, const float* __restrict__ bn1_b,
    const float* __restrict__ bn1_m, const float* __restrict__ bn1_v,
    unsigned int* __restrict__ mask)
{
    const int bid  = blockIdx.x;       // b*16 + word
    const int word = bid & 15;
    const int tid  = threadIdx.x;
    const int wv   = tid >> 6;         // wave 0..3
    const int lane = tid & 63;

    // per-wave padded tile: rows -1..28 (30 rows x 28 cols); rows -1,28 zero
    __shared__ float tile[4][30 * 28];
    __shared__ unsigned int wflags[4];

    float* tp = tile[wv] + 28;         // tp[r*28 + c], r in [-1, 28]

    // zero the two halo rows once (wave-local; DS ops in-order per wave)
    if (lane < 28)      tile[wv][lane] = 0.0f;                 // row -1
    else if (lane < 56) tile[wv][29 * 28 + lane - 28] = 0.0f;  // row 28

    const int    cbase = word * 32 + wv * 8;       // first channel of wave
    const float* xw    = x + ((size_t)bid * 32 + (size_t)wv * 8) * HWPLANE;

    // conv work assignment: lane -> (col pair j, row group g)
    const int   j   = lane % 14;                   // cols 2j, 2j+1
    const int   gg  = lane / 14;                   // 0..4 (56-63 duplicate g=3)
    const int   r0  = (gg < 4 ? gg : 3) * 7;       // rows r0 .. r0+6
    const float mL  = (j > 0)  ? 1.0f : 0.0f;
    const float mR  = (j < 13) ? 1.0f : 0.0f;
    const int   pL  = (j > 0)  ? 2 * j - 2 : 0;    // clamped (masked)
    const int   pC  = 2 * j;
    const int   pR  = (j < 13) ? 2 * j + 2 : 24;   // clamped (masked)

    // prefetch plane 0 (196 float4 slots; slot 192+(lane&3) loaded by all,
    // stored by lanes 0-3 only)
    float4 v0 = ((const float4*)xw)[lane];
    float4 v1 = ((const float4*)xw)[lane + 64];
    float4 v2 = ((const float4*)xw)[lane + 128];
    float4 v3 = ((const float4*)xw)[192 + (lane & 3)];

    unsigned int flags = 0;

    for (int p = 0; p < 8; ++p) {
        // stage current plane regs -> LDS (aligned b128)
        ((float4*)tp)[lane]       = v0;
        ((float4*)tp)[lane + 64]  = v1;
        ((float4*)tp)[lane + 128] = v2;
        if (lane < 4) ((float4*)tp)[lane + 192] = v3;

        // prefetch next plane into fresh regs (overlaps with conv below)
        float4 n0, n1, n2, n3;
        if (p < 7) {
            const float* xn = xw + (size_t)(p + 1) * HWPLANE;
            n0 = ((const float4*)xn)[lane];
            n1 = ((const float4*)xn)[lane + 64];
            n2 = ((const float4*)xn)[lane + 128];
            n3 = ((const float4*)xn)[192 + (lane & 3)];
        }

        // per-plane constants
        const int   c    = cbase + p;
        const float inv1 = bn1_g[c] * rsqrtf(bn1_v[c] + EPS);
        const float c1   = (dw_b[c] - bn1_m[c]) * inv1 + bn1_b[c];
        float w9[9];
        #pragma unroll
        for (int k = 0; k < 9; ++k) w9[k] = dw_w[c * 9 + k];

        float amax_l = 0.0f;   // ReLU folded into fmax (identity 0)
        {
            // rolling 3-row window, 4 cols each: (m1, 0, 1, 2)
            float2 La = *(const float2*)&tp[(r0 - 1) * 28 + pL];
            float2 Ca = *(const float2*)&tp[(r0 - 1) * 28 + pC];
            float2 Ra = *(const float2*)&tp[(r0 - 1) * 28 + pR];
            float2 Lb = *(const float2*)&tp[r0 * 28 + pL];
            float2 Cb = *(const float2*)&tp[r0 * 28 + pC];
            float2 Rb = *(const float2*)&tp[r0 * 28 + pR];
            float am1 = La.y * mL, a0 = Ca.x, a1 = Ca.y, a2 = Ra.x * mR;
            float bm1 = Lb.y * mL, b0 = Cb.x, b1 = Cb.y, b2 = Rb.x * mR;
            #pragma unroll
            for (int rr = 0; rr < 7; ++rr) {
                const int rc = r0 + rr + 1;
                float2 Lc = *(const float2*)&tp[rc * 28 + pL];
                float2 Cc = *(const float2*)&tp[rc * 28 + pC];
                float2 Rc = *(const float2*)&tp[rc * 28 + pR];
                float cm1 = Lc.y * mL, cc0 = Cc.x, cc1 = Cc.y, cc2 = Rc.x * mR;
                // pixel at col 2j
                float acc0 =              w9[0] * am1;
                acc0 = fmaf(w9[1], a0,  acc0);
                acc0 = fmaf(w9[2], a1,  acc0);
                acc0 = fmaf(w9[3], bm1, acc0);
                acc0 = fmaf(w9[4], b0,  acc0);
                acc0 = fmaf(w9[5], b1,  acc0);
                acc0 = fmaf(w9[6], cm1, acc0);
                acc0 = fmaf(w9[7], cc0, acc0);
                acc0 = fmaf(w9[8], cc1, acc0);
                // pixel at col 2j+1
                float acc1 =              w9[0] * a0;
                acc1 = fmaf(w9[1], a1,  acc1);
                acc1 = fmaf(w9[2], a2,  acc1);
                acc1 = fmaf(w9[3], b0,  acc1);
                acc1 = fmaf(w9[4], b1,  acc1);
                acc1 = fmaf(w9[5], b2,  acc1);
                acc1 = fmaf(w9[6], cc0, acc1);
                acc1 = fmaf(w9[7], cc1, acc1);
                acc1 = fmaf(w9[8], cc2, acc1);
                const float t0 = fmaf(acc0, inv1, c1);
                const float t1 = fmaf(acc1, inv1, c1);
                amax_l = fmaxf(amax_l, fmaxf(t0, t1));
                // rotate rows
                am1 = bm1; a0 = b0; a1 = b1; a2 = b2;
                bm1 = cm1; b0 = cc0; b1 = cc1; b2 = cc2;
            }
        }

        // full-wave max reduce (all 64 lanes hold valid/duplicate values)
        #pragma unroll
        for (int off = 1; off < 64; off <<= 1)
            amax_l = fmaxf(amax_l, __shfl_xor(amax_l, off, 64));
        if (amax_l >= DW_THRESH) flags |= (1u << p);

        if (p < 7) { v0 = n0; v1 = n1; v2 = n2; v3 = n3; }
    }

    if (lane == 0) wflags[wv] = flags;
    __syncthreads();
    if (tid == 0)
        mask[bid] = wflags[0] | (wflags[1] << 8) | (wflags[2] << 16)
                  | (wflags[3] << 24);
}

// ---------------------------------------------------------------------------
// Pass 2: pointwise 1x1 over ACTIVE channels (+bias+BN2+ReLU+prune).
// One block per (b, 32-output-channel group). Fast path (no active ci in the
// batch): 32 constant planes as one contiguous float4 store stream.
// ---------------------------------------------------------------------------
__global__ __launch_bounds__(256) void pw_kernel(
    const float* __restrict__ x,
    const float* __restrict__ dw_w, const float* __restrict__ dw_b,
    const float* __restrict__ bn1_g, const float* __restrict__ bn1_b,
    const float* __restrict__ bn1_m, const float* __restrict__ bn1_v,
    const float* __restrict__ pw_w, const float* __restrict__ pw_b,
    const float* __restrict__ bn2_g, const float* __restrict__ bn2_b,
    const float* __restrict__ bn2_m, const float* __restrict__ bn2_v,
    const unsigned int* __restrict__ mask,
    float* __restrict__ out)
{
    const int bid = blockIdx.x;            // b*16 + og
    const int b   = bid >> 4;
    const int og  = bid & 15;
    const int tid = threadIdx.x;

    __shared__ unsigned int smask[16];
    __shared__ float sconst[32];
    __shared__ float sx[30 * 30];
    __shared__ float red[4];
    __shared__ float sfinal;

    if (tid < 16) smask[tid] = mask[(b << 4) + tid];
    __syncthreads();

    unsigned int any = 0;
    #pragma unroll
    for (int k = 0; k < 16; ++k) any |= smask[k];

    float* ob = out + (size_t)bid * 32 * HWPLANE;   // 32 contiguous planes

    if (any == 0u) {
        if (tid < 32) {
            const int   co   = og * 32 + tid;
            const float inv2 = bn2_g[co] * rsqrtf(bn2_v[co] + EPS);
            const float c2   = (pw_b[co] - bn2_m[co]) * inv2 + bn2_b[co];
            float vv = c2 > 0.0f ? c2 : 0.0f;       // ReLU
            if (vv < PW_THRESH) vv = 0.0f;          // constant-plane prune
            sconst[tid] = vv;
        }
        __syncthreads();
        for (int jj = tid; jj < 6272; jj += 256) {  // 32 planes * 196 float4
            const float vv = sconst[jj / 196];
            ((float4*)ob)[jj] = make_float4(vv, vv, vv, vv);
        }
        return;
    }

    // ---- general path (correctness only; not taken with this data) ----
    for (int i = tid; i < 900; i += 256) sx[i] = 0.0f;   // halo zeros
    const int xx = tid % 28;
    const int ys = (tid / 28) * 4;

    for (int col = 0; col < 32; ++col) {
        const int co = og * 32 + col;
        const float inv2 = bn2_g[co] * rsqrtf(bn2_v[co] + EPS);
        const float c2   = (pw_b[co] - bn2_m[co]) * inv2 + bn2_b[co];
        float acc[4] = {0.f, 0.f, 0.f, 0.f};

        for (int ci = 0; ci < CIN; ++ci) {
            if (!((smask[ci >> 5] >> (ci & 31)) & 1u)) continue;  // uniform
            __syncthreads();   // protect sx before overwrite
            const float* xp = x + ((size_t)(b * CIN + ci)) * HWPLANE;
            if (tid < 196) {
                const float4 vv = ((const float4*)xp)[tid];
                const int y  = tid / 7;
                const int x0 = (tid % 7) * 4;
                float* d = &sx[(y + 1) * 30 + x0 + 1];
                d[0] = vv.x; d[1] = vv.y; d[2] = vv.z; d[3] = vv.w;
            }
            const float inv1 = bn1_g[ci] * rsqrtf(bn1_v[ci] + EPS);
            const float c1   = (dw_b[ci] - bn1_m[ci]) * inv1 + bn1_b[ci];
            const float wco  = pw_w[co * CIN + ci];
            float w9[9];
            #pragma unroll
            for (int k = 0; k < 9; ++k) w9[k] = dw_w[ci * 9 + k];
            __syncthreads();
            if (tid < 196) {
                float r[6][3];
                #pragma unroll
                for (int jj = 0; jj < 6; ++jj)
                    #pragma unroll
                    for (int k = 0; k < 3; ++k)
                        r[jj][k] = sx[(ys + jj) * 30 + xx + k];
                #pragma unroll
                for (int i = 0; i < 4; ++i) {
                    float a = 0.0f;
                    #pragma unroll
                    for (int dy = 0; dy < 3; ++dy)
                        #pragma unroll
                        for (int dx = 0; dx < 3; ++dx)
                            a = fmaf(w9[dy * 3 + dx], r[i + dy][dx], a);
                    float hv = fmaf(a, inv1, c1);
                    hv = hv > 0.0f ? hv : 0.0f;
                    acc[i] = fmaf(wco, hv, acc[i]);
                }
            }
        }

        float vout[4];
        float amax = 0.0f;
        if (tid < 196) {
            #pragma unroll
            for (int i = 0; i < 4; ++i) {
                float t = fmaf(acc[i], inv2, c2);
                t = t > 0.0f ? t : 0.0f;
                vout[i] = t;
                amax = fmaxf(amax, t);
            }
        }
        #pragma unroll
        for (int off = 32; off > 0; off >>= 1)
            amax = fmaxf(amax, __shfl_down(amax, off, 64));
        if ((tid & 63) == 0) red[tid >> 6] = amax;
        __syncthreads();
        if (tid == 0)
            sfinal = fmaxf(fmaxf(red[0], red[1]), fmaxf(red[2], red[3]));
        __syncthreads();
        const bool zero = sfinal < PW_THRESH;
        if (tid < 196) {
            float* op = ob + (size_t)col * HWPLANE;
            #pragma unroll
            for (int i = 0; i < 4; ++i)
                op[(ys + i) * 28 + xx] = zero ? 0.0f : vout[i];
        }
        __syncthreads();
    }
}

extern "C" void kernel_launch(void* const* d_in, const int* in_sizes, int n_in,
                              void* d_out, int out_size, void* d_ws, size_t ws_size,
                              hipStream_t stream)
{
    const float* x     = (const float*)d_in[0];
    const float* dw_w  = (const float*)d_in[1];
    const float* dw_b  = (const float*)d_in[2];
    const float* bn1_g = (const float*)d_in[3];
    const float* bn1_b = (const float*)d_in[4];
    const float* bn1_m = (const float*)d_in[5];
    const float* bn1_v = (const float*)d_in[6];
    const float* pw_w  = (const float*)d_in[7];
    const float* pw_b  = (const float*)d_in[8];
    const float* bn2_g = (const float*)d_in[9];
    const float* bn2_b = (const float*)d_in[10];
    const float* bn2_m = (const float*)d_in[11];
    const float* bn2_v = (const float*)d_in[12];

    unsigned int* mask = (unsigned int*)d_ws;  // 64 x 16 words, all written

    dw_flags_kernel<<<64 * 16, 256, 0, stream>>>(
        x, dw_w, dw_b, bn1_g, bn1_b, bn1_m, bn1_v, mask);

    pw_kernel<<<64 * 16, 256, 0, stream>>>(
        x, dw_w, dw_b, bn1_g, bn1_b, bn1_m, bn1_v,
        pw_w, pw_b, bn2_g, bn2_b, bn2_m, bn2_v,
        mask, (float*)d_out);
}

// Round 4
// 37.219 us; speedup vs baseline: 1.6894x; 1.0333x over previous
//
#include <hip/hip_runtime.h>

#define EPS        1e-5f
#define DW_THRESH  4.0f
#define PW_THRESH  0.001f
#define CIN        512
#define COUT       512
#define HWPLANE    784   // 28*28

// ---------------------------------------------------------------------------
// Pass 1: per-(b,c) plane activity flags.
// One block per (b, 32-channel word): 1024 blocks, 4 waves/block, 8 planes
// per wave, wave-autonomous (no __syncthreads in the hot loop).
// FAST PATH: plane abs-max m from the prefetch registers gives a rigorous
// bound  t <= |inv1|*sum|w9|*m + c1.  If that bound < DW_THRESH the plane is
// provably pruned -- skip LDS staging and the conv entirely.
// EXACT PATH (rare): stage plane to the wave's padded LDS tile and run the
// exact 3x3 conv + BN1 + ReLU + amax (identical to the verified round-3 code).
// ---------------------------------------------------------------------------
__global__ __launch_bounds__(256) void dw_flags_kernel(
    const float* __restrict__ x,
    const float* __restrict__ dw_w, const float* __restrict__ dw_b,
    const float* __restrict__ bn1_g, const float* __restrict__ bn1_b,
    const float* __restrict__ bn1_m, const float* __restrict__ bn1_v,
    unsigned int* __restrict__ mask)
{
    const int bid  = blockIdx.x;       // b*16 + word
    const int word = bid & 15;
    const int tid  = threadIdx.x;
    const int wv   = tid >> 6;         // wave 0..3
    const int lane = tid & 63;

    // per-wave padded tile: rows -1..28 (30 rows x 28 cols); rows -1,28 zero
    __shared__ float tile[4][30 * 28];
    __shared__ unsigned int wflags[4];

    float* tp = tile[wv] + 28;         // tp[r*28 + c], r in [-1, 28]

    // zero the two halo rows once (wave-local; DS ops in-order per wave)
    if (lane < 28)      tile[wv][lane] = 0.0f;                 // row -1
    else if (lane < 56) tile[wv][29 * 28 + lane - 28] = 0.0f;  // row 28

    const int    cbase = word * 32 + wv * 8;       // first channel of wave
    const float* xw    = x + ((size_t)bid * 32 + (size_t)wv * 8) * HWPLANE;

    // conv work assignment (exact path): lane -> (col pair j, row group g)
    const int   j   = lane % 14;                   // cols 2j, 2j+1
    const int   gg  = lane / 14;                   // 0..4 (56-63 duplicate g=3)
    const int   r0  = (gg < 4 ? gg : 3) * 7;       // rows r0 .. r0+6
    const float mLm = (j > 0)  ? 1.0f : 0.0f;
    const float mRm = (j < 13) ? 1.0f : 0.0f;
    const int   pL  = (j > 0)  ? 2 * j - 2 : 0;    // clamped (masked)
    const int   pC  = 2 * j;
    const int   pR  = (j < 13) ? 2 * j + 2 : 24;   // clamped (masked)

    // prefetch plane 0 (196 float4 slots; slot 192+(lane&3) duplicated)
    float4 v0 = ((const float4*)xw)[lane];
    float4 v1 = ((const float4*)xw)[lane + 64];
    float4 v2 = ((const float4*)xw)[lane + 128];
    float4 v3 = ((const float4*)xw)[192 + (lane & 3)];

    unsigned int flags = 0;

    for (int p = 0; p < 8; ++p) {
        // prefetch next plane first (overlaps everything below)
        float4 n0, n1, n2, n3;
        if (p < 7) {
            const float* xn = xw + (size_t)(p + 1) * HWPLANE;
            n0 = ((const float4*)xn)[lane];
            n1 = ((const float4*)xn)[lane + 64];
            n2 = ((const float4*)xn)[lane + 128];
            n3 = ((const float4*)xn)[192 + (lane & 3)];
        }

        // plane abs-max from registers (duplicated slots are harmless for max)
        float m = fabsf(v0.x);
        m = fmaxf(m, fabsf(v0.y)); m = fmaxf(m, fabsf(v0.z));
        m = fmaxf(m, fabsf(v0.w)); m = fmaxf(m, fabsf(v1.x));
        m = fmaxf(m, fabsf(v1.y)); m = fmaxf(m, fabsf(v1.z));
        m = fmaxf(m, fabsf(v1.w)); m = fmaxf(m, fabsf(v2.x));
        m = fmaxf(m, fabsf(v2.y)); m = fmaxf(m, fabsf(v2.z));
        m = fmaxf(m, fabsf(v2.w)); m = fmaxf(m, fabsf(v3.x));
        m = fmaxf(m, fabsf(v3.y)); m = fmaxf(m, fabsf(v3.z));
        m = fmaxf(m, fabsf(v3.w));
        #pragma unroll
        for (int off = 1; off < 64; off <<= 1)
            m = fmaxf(m, __shfl_xor(m, off, 64));

        // per-plane constants (block-uniform -> scalar loads)
        const int   c    = cbase + p;
        const float inv1 = bn1_g[c] * rsqrtf(bn1_v[c] + EPS);
        const float c1   = (dw_b[c] - bn1_m[c]) * inv1 + bn1_b[c];
        float w9[9];
        #pragma unroll
        for (int k = 0; k < 9; ++k) w9[k] = dw_w[c * 9 + k];
        float S = fabsf(w9[0]);
        #pragma unroll
        for (int k = 1; k < 9; ++k) S += fabsf(w9[k]);

        // rigorous upper bound on pre-ReLU output over the whole plane
        const float ub = fabsf(inv1) * S * m + c1;

        if (ub >= DW_THRESH * 0.999f) {
            // ---- exact path (rare): stage to LDS and convolve ----
            ((float4*)tp)[lane]       = v0;
            ((float4*)tp)[lane + 64]  = v1;
            ((float4*)tp)[lane + 128] = v2;
            if (lane < 4) ((float4*)tp)[lane + 192] = v3;

            float amax_l = 0.0f;   // ReLU folded into fmax
            float2 La = *(const float2*)&tp[(r0 - 1) * 28 + pL];
            float2 Ca = *(const float2*)&tp[(r0 - 1) * 28 + pC];
            float2 Ra = *(const float2*)&tp[(r0 - 1) * 28 + pR];
            float2 Lb = *(const float2*)&tp[r0 * 28 + pL];
            float2 Cb = *(const float2*)&tp[r0 * 28 + pC];
            float2 Rb = *(const float2*)&tp[r0 * 28 + pR];
            float am1 = La.y * mLm, a0 = Ca.x, a1 = Ca.y, a2 = Ra.x * mRm;
            float bm1 = Lb.y * mLm, b0 = Cb.x, b1 = Cb.y, b2 = Rb.x * mRm;
            #pragma unroll
            for (int rr = 0; rr < 7; ++rr) {
                const int rc = r0 + rr + 1;
                float2 Lc = *(const float2*)&tp[rc * 28 + pL];
                float2 Cc = *(const float2*)&tp[rc * 28 + pC];
                float2 Rc = *(const float2*)&tp[rc * 28 + pR];
                float cm1 = Lc.y * mLm, cc0 = Cc.x, cc1 = Cc.y, cc2 = Rc.x * mRm;
                float acc0 =              w9[0] * am1;
                acc0 = fmaf(w9[1], a0,  acc0);
                acc0 = fmaf(w9[2], a1,  acc0);
                acc0 = fmaf(w9[3], bm1, acc0);
                acc0 = fmaf(w9[4], b0,  acc0);
                acc0 = fmaf(w9[5], b1,  acc0);
                acc0 = fmaf(w9[6], cm1, acc0);
                acc0 = fmaf(w9[7], cc0, acc0);
                acc0 = fmaf(w9[8], cc1, acc0);
                float acc1 =              w9[0] * a0;
                acc1 = fmaf(w9[1], a1,  acc1);
                acc1 = fmaf(w9[2], a2,  acc1);
                acc1 = fmaf(w9[3], b0,  acc1);
                acc1 = fmaf(w9[4], b1,  acc1);
                acc1 = fmaf(w9[5], b2,  acc1);
                acc1 = fmaf(w9[6], cc0, acc1);
                acc1 = fmaf(w9[7], cc1, acc1);
                acc1 = fmaf(w9[8], cc2, acc1);
                const float t0 = fmaf(acc0, inv1, c1);
                const float t1 = fmaf(acc1, inv1, c1);
                amax_l = fmaxf(amax_l, fmaxf(t0, t1));
                am1 = bm1; a0 = b0; a1 = b1; a2 = b2;
                bm1 = cm1; b0 = cc0; b1 = cc1; b2 = cc2;
            }
            #pragma unroll
            for (int off = 1; off < 64; off <<= 1)
                amax_l = fmaxf(amax_l, __shfl_xor(amax_l, off, 64));
            if (amax_l >= DW_THRESH) flags |= (1u << p);
        }
        // else: provably pruned, bit stays 0

        if (p < 7) { v0 = n0; v1 = n1; v2 = n2; v3 = n3; }
    }

    if (lane == 0) wflags[wv] = flags;
    __syncthreads();
    if (tid == 0)
        mask[bid] = wflags[0] | (wflags[1] << 8) | (wflags[2] << 16)
                  | (wflags[3] << 24);
}

// ---------------------------------------------------------------------------
// Pass 2: pointwise 1x1 over ACTIVE channels (+bias+BN2+ReLU+prune).
// One block per (b, 32-output-channel group). Fast path (no active ci in the
// batch): 32 constant planes as one contiguous float4 store stream.
// ---------------------------------------------------------------------------
__global__ __launch_bounds__(256) void pw_kernel(
    const float* __restrict__ x,
    const float* __restrict__ dw_w, const float* __restrict__ dw_b,
    const float* __restrict__ bn1_g, const float* __restrict__ bn1_b,
    const float* __restrict__ bn1_m, const float* __restrict__ bn1_v,
    const float* __restrict__ pw_w, const float* __restrict__ pw_b,
    const float* __restrict__ bn2_g, const float* __restrict__ bn2_b,
    const float* __restrict__ bn2_m, const float* __restrict__ bn2_v,
    const unsigned int* __restrict__ mask,
    float* __restrict__ out)
{
    const int bid = blockIdx.x;            // b*16 + og
    const int b   = bid >> 4;
    const int og  = bid & 15;
    const int tid = threadIdx.x;

    __shared__ unsigned int smask[16];
    __shared__ float sconst[32];
    __shared__ float sx[30 * 30];
    __shared__ float red[4];
    __shared__ float sfinal;

    if (tid < 16) smask[tid] = mask[(b << 4) + tid];
    __syncthreads();

    unsigned int any = 0;
    #pragma unroll
    for (int k = 0; k < 16; ++k) any |= smask[k];

    float* ob = out + (size_t)bid * 32 * HWPLANE;   // 32 contiguous planes

    if (any == 0u) {
        if (tid < 32) {
            const int   co   = og * 32 + tid;
            const float inv2 = bn2_g[co] * rsqrtf(bn2_v[co] + EPS);
            const float c2   = (pw_b[co] - bn2_m[co]) * inv2 + bn2_b[co];
            float vv = c2 > 0.0f ? c2 : 0.0f;       // ReLU
            if (vv < PW_THRESH) vv = 0.0f;          // constant-plane prune
            sconst[tid] = vv;
        }
        __syncthreads();
        for (int jj = tid; jj < 6272; jj += 256) {  // 32 planes * 196 float4
            const float vv = sconst[jj / 196];
            ((float4*)ob)[jj] = make_float4(vv, vv, vv, vv);
        }
        return;
    }

    // ---- general path (correctness only; not taken with this data) ----
    for (int i = tid; i < 900; i += 256) sx[i] = 0.0f;   // halo zeros
    const int xx = tid % 28;
    const int ys = (tid / 28) * 4;

    for (int col = 0; col < 32; ++col) {
        const int co = og * 32 + col;
        const float inv2 = bn2_g[co] * rsqrtf(bn2_v[co] + EPS);
        const float c2   = (pw_b[co] - bn2_m[co]) * inv2 + bn2_b[co];
        float acc[4] = {0.f, 0.f, 0.f, 0.f};

        for (int ci = 0; ci < CIN; ++ci) {
            if (!((smask[ci >> 5] >> (ci & 31)) & 1u)) continue;  // uniform
            __syncthreads();   // protect sx before overwrite
            const float* xp = x + ((size_t)(b * CIN + ci)) * HWPLANE;
            if (tid < 196) {
                const float4 vv = ((const float4*)xp)[tid];
                const int y  = tid / 7;
                const int x0 = (tid % 7) * 4;
                float* d = &sx[(y + 1) * 30 + x0 + 1];
                d[0] = vv.x; d[1] = vv.y; d[2] = vv.z; d[3] = vv.w;
            }
            const float inv1 = bn1_g[ci] * rsqrtf(bn1_v[ci] + EPS);
            const float c1   = (dw_b[ci] - bn1_m[ci]) * inv1 + bn1_b[ci];
            const float wco  = pw_w[co * CIN + ci];
            float w9[9];
            #pragma unroll
            for (int k = 0; k < 9; ++k) w9[k] = dw_w[ci * 9 + k];
            __syncthreads();
            if (tid < 196) {
                float r[6][3];
                #pragma unroll
                for (int jj = 0; jj < 6; ++jj)
                    #pragma unroll
                    for (int k = 0; k < 3; ++k)
                        r[jj][k] = sx[(ys + jj) * 30 + xx + k];
                #pragma unroll
                for (int i = 0; i < 4; ++i) {
                    float a = 0.0f;
                    #pragma unroll
                    for (int dy = 0; dy < 3; ++dy)
                        #pragma unroll
                        for (int dx = 0; dx < 3; ++dx)
                            a = fmaf(w9[dy * 3 + dx], r[i + dy][dx], a);
                    float hv = fmaf(a, inv1, c1);
                    hv = hv > 0.0f ? hv : 0.0f;
                    acc[i] = fmaf(wco, hv, acc[i]);
                }
            }
        }

        float vout[4];
        float amax = 0.0f;
        if (tid < 196) {
            #pragma unroll
            for (int i = 0; i < 4; ++i) {
                float t = fmaf(acc[i], inv2, c2);
                t = t > 0.0f ? t : 0.0f;
                vout[i] = t;
                amax = fmaxf(amax, t);
            }
        }
        #pragma unroll
        for (int off = 32; off > 0; off >>= 1)
            amax = fmaxf(amax, __shfl_down(amax, off, 64));
        if ((tid & 63) == 0) red[tid >> 6] = amax;
        __syncthreads();
        if (tid == 0)
            sfinal = fmaxf(fmaxf(red[0], red[1]), fmaxf(red[2], red[3]));
        __syncthreads();
        const bool zero = sfinal < PW_THRESH;
        if (tid < 196) {
            float* op = ob + (size_t)col * HWPLANE;
            #pragma unroll
            for (int i = 0; i < 4; ++i)
                op[(ys + i) * 28 + xx] = zero ? 0.0f : vout[i];
        }
        __syncthreads();
    }
}

extern "C" void kernel_launch(void* const* d_in, const int* in_sizes, int n_in,
                              void* d_out, int out_size, void* d_ws, size_t ws_size,
                              hipStream_t stream)
{
    const float* x     = (const float*)d_in[0];
    const float* dw_w  = (const float*)d_in[1];
    const float* dw_b  = (const float*)d_in[2];
    const float* bn1_g = (const float*)d_in[3];
    const float* bn1_b = (const float*)d_in[4];
    const float* bn1_m = (const float*)d_in[5];
    const float* bn1_v = (const float*)d_in[6];
    const float* pw_w  = (const float*)d_in[7];
    const float* pw_b  = (const float*)d_in[8];
    const float* bn2_g = (const float*)d_in[9];
    const float* bn2_b = (const float*)d_in[10];
    const float* bn2_m = (const float*)d_in[11];
    const float* bn2_v = (const float*)d_in[12];

    unsigned int* mask = (unsigned int*)d_ws;  // 64 x 16 words, all written

    dw_flags_kernel<<<64 * 16, 256, 0, stream>>>(
        x, dw_w, dw_b, bn1_g, bn1_b, bn1_m, bn1_v, mask);

    pw_kernel<<<64 * 16, 256, 0, stream>>>(
        x, dw_w, dw_b, bn1_g, bn1_b, bn1_m, bn1_v,
        pw_w, pw_b, bn2_g, bn2_b, bn2_m, bn2_v,
        mask, (float*)d_out);
}